// Round 1
// baseline (5057.355 us; speedup 1.0000x reference)
//
#include <hip/hip_runtime.h>

#define H      27
#define H4     108
#define TT     78
#define NB     32768
#define LAYERS 3
#define WAVES  9
#define BLOCK  (WAVES * 64)   // 576 threads, 9 waves per block
#define JPW    3              // j-rows per wave: 27 / 9, perfectly balanced

#define LOG2E 1.4426950408889634f

__device__ __forceinline__ float fast_rcp(float x)  { return __builtin_amdgcn_rcpf(x); }
__device__ __forceinline__ float fast_exp2(float x) { return __builtin_amdgcn_exp2f(x); }
// sigmoid(a) = 1/(1+2^(-log2e*a)) ; tanh(a) = -1 + 2/(1+2^(-2log2e*a))
__device__ __forceinline__ float sigm_f(float a) { return fast_rcp(1.f + fast_exp2(-LOG2E * a)); }
__device__ __forceinline__ float tanh_f(float a) { return -1.f + 2.f * fast_rcp(1.f + fast_exp2(-2.f * LOG2E * a)); }

// Structure: block = 64 batch elements (lane = batch elem), 9 waves.
// Wave w owns output rows j in [3w, 3w+3) and computes ALL FOUR gates for
// those j -> gates never leave registers (no gbuf, no gate-exchange barrier).
// Weight addresses are wave-uniform -> s_load / SGPR-broadcast FMA operands.
// h state is ping-pong buffered (read hbuf[cur], write hbuf[nxt]) so each
// layer needs exactly ONE barrier (RAW on the new h). 5 barriers/timestep
// vs 8 before. grid = 512 blocks x 9 waves = 4608 waves = 4.5/SIMD (~56% occ).
__launch_bounds__(BLOCK, 4)
__global__ void lstm3_fused(const float* __restrict__ x,
                            const float* __restrict__ h0,
                            const float* __restrict__ c0,
                            const float* __restrict__ Wih,
                            const float* __restrict__ Whh,
                            const float* __restrict__ bih,
                            const float* __restrict__ bhh,
                            const float* __restrict__ Wl,
                            const float* __restrict__ bl,
                            float* __restrict__ out)
{
    __shared__ float xbuf[H * 65];                 // staged x_t, [k*65 + bi]
    __shared__ float hbuf[2][LAYERS][H * 64];      // ping-pong h, [k*64 + bi] (2 lanes/bank = free)
    __shared__ float obuf[H * 65];                 // staged output

    const int tid   = threadIdx.x;
    const int w     = __builtin_amdgcn_readfirstlane(tid >> 6); // wave id 0..8 (uniform)
    const int lane  = tid & 63;                                  // batch element in group
    const int bbase = blockIdx.x * 64;
    const int jbeg  = w * JPW;

    // ---- init: stage h0 -> hbuf[0] (one-time) ----
    for (int e = tid; e < LAYERS * 64 * H; e += BLOCK) {
        int l  = e / (64 * H);
        int r  = e - l * (64 * H);
        int bi = r / H;
        int k  = r - bi * H;
        hbuf[0][l][k * 64 + bi] = h0[(size_t)l * NB * H + (size_t)(bbase + bi) * H + k];
    }
    // c0 -> regs (one-time scattered loads, tiny). Lane holds c for its 3 j's.
    float c[LAYERS][JPW];
    #pragma unroll
    for (int l = 0; l < LAYERS; ++l)
        #pragma unroll
        for (int jj = 0; jj < JPW; ++jj)
            c[l][jj] = c0[(size_t)l * NB * H + (size_t)(bbase + lane) * H + (jbeg + jj)];
    __syncthreads();

    int cur = 0;
    for (int t = 0; t < TT; ++t) {
        // ---- stage x_t cooperatively (coalesced 27-dword runs); 1728 = 3*576 exact ----
        for (int e = tid; e < 64 * H; e += BLOCK) {
            int bi = e / H;
            int k  = e - bi * H;
            xbuf[k * 65 + bi] = x[((size_t)(bbase + bi) * TT + t) * H + k];
        }
        __syncthreads();                       // B1: xbuf visible (also fences prev obuf store)
        const int nxt = cur ^ 1;

        #pragma unroll
        for (int l = 0; l < LAYERS; ++l) {
            // lane's input vector and h_prev -> regs (conflict-free LDS reads)
            float xr[H], hr[H];
            const float* xin = (l == 0) ? xbuf : &hbuf[nxt][l - 1][0];
            const int    xs  = (l == 0) ? 65 : 64;
            #pragma unroll
            for (int k = 0; k < H; ++k) {
                xr[k] = xin[k * xs + lane];
                hr[k] = hbuf[cur][l][k * 64 + lane];
            }

            const float* wiL = Wih + (size_t)l * H4 * H;
            const float* whL = Whh + (size_t)l * H4 * H;
            const float* b1L = bih + l * H4;
            const float* b2L = bhh + l * H4;

            // 3 j-rows x 4 gates = 12 rows, 54 FMAs each, weights via SGPR
            #pragma unroll
            for (int jj = 0; jj < JPW; ++jj) {
                const int j = jbeg + jj;
                float acc[4];
                #pragma unroll
                for (int g = 0; g < 4; ++g) {
                    const int row = g * H + j;
                    const float* wi = wiL + row * H;
                    const float* wh = whL + row * H;
                    float a = b1L[row] + b2L[row];
                    #pragma unroll
                    for (int k = 0; k < H; ++k) a += wi[k] * xr[k];
                    #pragma unroll
                    for (int k = 0; k < H; ++k) a += wh[k] * hr[k];
                    acc[g] = a;
                }
                const float ig = sigm_f(acc[0]);
                const float fg = sigm_f(acc[1]);
                const float gg = tanh_f(acc[2]);
                const float og = sigm_f(acc[3]);
                const float cn = fg * c[l][jj] + ig * gg;
                c[l][jj] = cn;
                hbuf[nxt][l][j * 64 + lane] = og * tanh_f(cn);
            }
            __syncthreads();                   // RAW: new h visible to next layer
        }

        // ---- final linear on layer-2 h (3 rows per wave) ----
        {
            float h2[H];
            #pragma unroll
            for (int k = 0; k < H; ++k) h2[k] = hbuf[nxt][2][k * 64 + lane];
            #pragma unroll
            for (int jj = 0; jj < JPW; ++jj) {
                const int j = jbeg + jj;
                float a = bl[j];
                #pragma unroll
                for (int k = 0; k < H; ++k) a += Wl[j * H + k] * h2[k];
                obuf[j * 65 + lane] = a;
            }
        }
        __syncthreads();                       // B5: obuf visible

        // ---- cooperative coalesced store ----
        for (int e = tid; e < 64 * H; e += BLOCK) {
            int bi = e / H;
            int k  = e - bi * H;
            out[((size_t)(bbase + bi) * TT + t) * H + k] = obuf[k * 65 + bi];
        }
        cur = nxt;                             // next iter's B1 fences the store loop
    }
}

extern "C" void kernel_launch(void* const* d_in, const int* in_sizes, int n_in,
                              void* d_out, int out_size, void* d_ws, size_t ws_size,
                              hipStream_t stream) {
    (void)in_sizes; (void)n_in; (void)ws_size; (void)d_ws; (void)out_size;
    const float* x   = (const float*)d_in[0];
    const float* h0  = (const float*)d_in[1];
    const float* c0  = (const float*)d_in[2];
    const float* Wih = (const float*)d_in[3];
    const float* Whh = (const float*)d_in[4];
    const float* bih = (const float*)d_in[5];
    const float* bhh = (const float*)d_in[6];
    const float* Wl  = (const float*)d_in[7];
    const float* bl  = (const float*)d_in[8];
    float* out = (float*)d_out;

    lstm3_fused<<<dim3(NB / 64), dim3(BLOCK), 0, stream>>>(
        x, h0, c0, Wih, Whh, bih, bhh, Wl, bl, out);
}